// Round 2
// baseline (763.463 us; speedup 1.0000x reference)
//
#include <hip/hip_runtime.h>
#include <stdint.h>

#define NPER  25000
#define NNODE 50000
#define NEDGE 600000
#define NREL  8
#define NBASE 4
#define INDIM 256
#define HIDD  128
#define OUTD  64
#define NSEG  (NNODE * NREL)

typedef unsigned short u16;
typedef unsigned int   u32;
typedef __attribute__((ext_vector_type(8))) __bf16          bf16x8;
typedef __attribute__((ext_vector_type(8))) unsigned short  ushort8;
typedef __attribute__((ext_vector_type(4))) float           f32x4;
typedef __attribute__((ext_vector_type(2))) float           f32x2;

__device__ __forceinline__ u16 f2b(float f) {
    union { __bf16 h; u16 u; } v; v.h = (__bf16)f; return v.u;   // HW RNE cvt
}
__device__ __forceinline__ bf16x8 as_bf(ushort8 u) {
    union { ushort8 a; bf16x8 b; } v; v.a = u; return v.b;
}
__device__ __forceinline__ bf16x8 cvt8(const float* p) {
    f32x4 f0 = *(const f32x4*)p;
    f32x4 f1 = *(const f32x4*)(p + 4);
    ushort8 u;
#pragma unroll
    for (int i = 0; i < 4; i++) { u[i] = f2b(f0[i]); u[i + 4] = f2b(f1[i]); }
    return as_bf(u);
}

// ---------------- weight repack (fp32 in -> bf16 transposed out) ----------------
// Wt[o][k] = W[k][o]
__global__ void transpose_kernel(const float* __restrict__ in, u16* __restrict__ out,
                                 int K, int Nc) {
    int idx = blockIdx.x * blockDim.x + threadIdx.x;
    if (idx >= K * Nc) return;
    int o = idx / K, k = idx % K;
    out[idx] = f2b(in[(size_t)k * Nc + o]);
}

// Wt[o][k] for conv: k<512 -> bases (as [512,outd]), else root[k-512][o]
__global__ void build_wt_conv_kernel(const float* __restrict__ bases, const float* __restrict__ root,
                                     int outd, u16* __restrict__ Wt) {
    int idx = blockIdx.x * blockDim.x + threadIdx.x;
    if (idx >= outd * 640) return;
    int o = idx / 640, k = idx % 640;
    float v = (k < 512) ? bases[(size_t)k * outd + o] : root[(size_t)(k - 512) * outd + o];
    Wt[idx] = f2b(v);
}

// ---------------- CSR build over seg = dst*8 + etype ----------------
__global__ void hist_kernel(const int* __restrict__ ei, const int* __restrict__ et,
                            int* __restrict__ cnt) {
    int e = blockIdx.x * blockDim.x + threadIdx.x;
    if (e >= NEDGE) return;
    int dst = ei[NEDGE + e];
    int r   = et[e];
    atomicAdd(&cnt[dst * NREL + r], 1);
}

#define SCAN_CHUNK 1024
__global__ void scan1_kernel(int* __restrict__ data, int n, int* __restrict__ bsum) {
    __shared__ int sh[256];
    int t = threadIdx.x;
    int base = blockIdx.x * SCAN_CHUNK + t * 4;
    int v[4];
#pragma unroll
    for (int i = 0; i < 4; i++) v[i] = (base + i < n) ? data[base + i] : 0;
    int tot = v[0] + v[1] + v[2] + v[3];
    sh[t] = tot; __syncthreads();
    for (int off = 1; off < 256; off <<= 1) {
        int x = (t >= off) ? sh[t - off] : 0;
        __syncthreads();
        sh[t] += x;
        __syncthreads();
    }
    int excl = sh[t] - tot;
    if (t == 255) bsum[blockIdx.x] = sh[255];
    int run = excl;
#pragma unroll
    for (int i = 0; i < 4; i++) {
        if (base + i < n) data[base + i] = run;
        run += v[i];
    }
}

__global__ void scan2_kernel(int* __restrict__ bsum, int nb) {
    __shared__ int sh[512];
    int t = threadIdx.x;
    int v = (t < nb) ? bsum[t] : 0;
    sh[t] = v; __syncthreads();
    for (int off = 1; off < 512; off <<= 1) {
        int x = (t >= off) ? sh[t - off] : 0;
        __syncthreads();
        sh[t] += x;
        __syncthreads();
    }
    if (t < nb) bsum[t] = sh[t] - v;
}

__global__ void scan3_kernel(int* __restrict__ data, int n, const int* __restrict__ bsum) {
    int add = bsum[blockIdx.x];
    int base = blockIdx.x * SCAN_CHUNK + threadIdx.x * 4;
#pragma unroll
    for (int i = 0; i < 4; i++)
        if (base + i < n) data[base + i] += add;
}

__global__ void scatter_kernel(const int* __restrict__ ei, const int* __restrict__ et,
                               int* __restrict__ fill, int* __restrict__ esrc) {
    int e = blockIdx.x * blockDim.x + threadIdx.x;
    if (e >= NEDGE) return;
    int src = ei[e];
    int dst = ei[NEDGE + e];
    int r   = et[e];
    int pos = atomicAdd(&fill[dst * NREL + r], 1);
    esrc[pos] = src;
}

// ---------------- fused mean-aggregate + comp contraction ----------------
// One wave per node; lane handles channels (2*lane, 2*lane+1). x is fp32.
// Writes Abuf[node][0:512] = agg2 (b-major, bf16), Abuf[node][512:640] = x[node] (bf16).
__global__ __launch_bounds__(256) void agg_kernel(
    const float* __restrict__ x, const float* __restrict__ comp,
    const int* __restrict__ rowptr, const int* __restrict__ esrc,
    u16* __restrict__ Abuf) {
    int tid  = threadIdx.x;
    int lane = tid & 63;
    int node = blockIdx.x * 4 + (tid >> 6);
    int c0   = lane * 2;
    float a0[NBASE] = {0.f, 0.f, 0.f, 0.f};
    float a1[NBASE] = {0.f, 0.f, 0.f, 0.f};
    int segbase = node * NREL;
#pragma unroll
    for (int r = 0; r < NREL; r++) {
        int s  = rowptr[segbase + r];
        int e_ = rowptr[segbase + r + 1];
        float s0 = 0.f, s1 = 0.f;
        for (int p = s; p < e_; p++) {
            int sn = esrc[p];
            f32x2 u = *(const f32x2*)(x + (size_t)sn * HIDD + c0);
            s0 += u[0];
            s1 += u[1];
        }
        int cnt = e_ - s;
        if (cnt > 0) { float nr = 1.f / (float)cnt; s0 *= nr; s1 *= nr; }
#pragma unroll
        for (int b = 0; b < NBASE; b++) {
            float cb = comp[r * NBASE + b];
            a0[b] += cb * s0;
            a1[b] += cb * s1;
        }
    }
    size_t obase = (size_t)node * 640;
#pragma unroll
    for (int b = 0; b < NBASE; b++) {
        u32 pk = (u32)f2b(a0[b]) | ((u32)f2b(a1[b]) << 16);
        *(u32*)(Abuf + obase + b * HIDD + c0) = pk;
    }
    f32x2 xv = *(const f32x2*)(x + (size_t)node * HIDD + c0);
    *(u32*)(Abuf + obase + 512 + c0) = (u32)f2b(xv[0]) | ((u32)f2b(xv[1]) << 16);
}

// ---------------- MFMA bf16 GEMM: out = epilogue(A[M,K] @ Wt^T + bias), fp32 out ------
// A is fp32 (AF32=true) or bf16 u16 (AF32=false). Wt is [Ncols, K] bf16 (pre-transposed).
// Block = 4 waves, 64-row tile, NT 16-col tiles.
template<int NT, bool RELU, bool RES, bool AF32>
__global__ __launch_bounds__(256) void gemm_bf16_kernel(
    const void* __restrict__ Av, const u16* __restrict__ Wt, int K,
    const float* __restrict__ bias, int M,
    float* __restrict__ out1, float* __restrict__ out2,
    const float* __restrict__ resid, int ldo) {
    int tid  = threadIdx.x;
    int wave = tid >> 6, lane = tid & 63;
    int l15  = lane & 15, quad = lane >> 4;
    int rowA = blockIdx.x * 64 + wave * 16 + l15;
    if (rowA > M - 1) rowA = M - 1;
    f32x4 acc[NT];
#pragma unroll
    for (int i = 0; i < NT; i++) acc[i] = (f32x4){0.f, 0.f, 0.f, 0.f};
    for (int k0 = 0; k0 < K; k0 += 32) {
        bf16x8 a;
        if (AF32) {
            const float* Ap = (const float*)Av + (size_t)rowA * K + quad * 8 + k0;
            a = cvt8(Ap);
        } else {
            const u16* Ap = (const u16*)Av + (size_t)rowA * K + quad * 8 + k0;
            a = as_bf(*(const ushort8*)Ap);
        }
#pragma unroll
        for (int nt = 0; nt < NT; nt++) {
            bf16x8 b = as_bf(*(const ushort8*)(Wt + (size_t)(nt * 16 + l15) * K + k0 + quad * 8));
            acc[nt] = __builtin_amdgcn_mfma_f32_16x16x32_bf16(a, b, acc[nt], 0, 0, 0);
        }
    }
    int orow0 = blockIdx.x * 64 + wave * 16 + quad * 4;
#pragma unroll
    for (int r = 0; r < 4; r++) {
        int orow = orow0 + r;
        if (orow < M) {
#pragma unroll
            for (int nt = 0; nt < NT; nt++) {
                int col = nt * 16 + l15;
                float v = acc[nt][r] + bias[col];
                if (RELU) v = v > 0.f ? v : 0.f;
                if (RES)  v += resid[(size_t)orow * ldo + col];
                out1[(size_t)orow * ldo + col] = v;
                if (out2) out2[(size_t)orow * ldo + col] = v;
            }
        }
    }
}

extern "C" void kernel_launch(void* const* d_in, const int* in_sizes, int n_in,
                              void* d_out, int out_size, void* d_ws, size_t ws_size,
                              hipStream_t stream) {
    const float* x_paper  = (const float*)d_in[0];
    const float* x_author = (const float*)d_in[1];
    const float* W_paper  = (const float*)d_in[2];
    const float* b_paper  = (const float*)d_in[3];
    const float* W_author = (const float*)d_in[4];
    const float* b_author = (const float*)d_in[5];
    const float* bases0   = (const float*)d_in[6];
    const float* comp0    = (const float*)d_in[7];
    const float* root0    = (const float*)d_in[8];
    const float* bias0    = (const float*)d_in[9];
    const float* bases1   = (const float*)d_in[10];
    const float* comp1    = (const float*)d_in[11];
    const float* root1    = (const float*)d_in[12];
    const float* bias1    = (const float*)d_in[13];
    const float* bases2   = (const float*)d_in[14];
    const float* comp2    = (const float*)d_in[15];
    const float* root2    = (const float*)d_in[16];
    const float* bias2    = (const float*)d_in[17];
    const int* ei         = (const int*)d_in[18];
    const int* et         = (const int*)d_in[19];

    float* ob   = (float*)d_out;
    float* outF = ob;                         // [50000,64]
    float* lat0 = ob + 3200000;               // x0
    float* lat1 = ob + 9600000;               // x0 (copy)
    float* lat2 = ob + 16000000;              // x1

    char* w = (char*)d_ws;
    u16*   Abuf   = (u16*)(w + 0);            // 50000*640*2  = 64,000,000
    float* x2     = (float*)(w + 64000000);   // 50000*128*4  = 25,600,000
    u16*   Wt     = (u16*)(w + 89600000);     // 128*640*2    =    163,840
    u16*   Wtp    = (u16*)(w + 89763840);     // 128*256*2    =     65,536
    u16*   Wta    = (u16*)(w + 89829376);     // 128*256*2    =     65,536
    int*   rowptr = (int*)(w + 89894912);     // 400001*4     ~  1,600,004
    int*   fill   = (int*)(w + 91495168);     // 400000*4     =  1,600,000
    int*   esrc   = (int*)(w + 93095168);     // 600000*4     =  2,400,000
    int*   bsum   = (int*)(w + 95495168);     // 512*4

    // ---- projections: x0 = relu(x @ W + b), written to both latent copies ----
    transpose_kernel<<<(INDIM * HIDD + 255) / 256, 256, 0, stream>>>(W_paper, Wtp, INDIM, HIDD);
    transpose_kernel<<<(INDIM * HIDD + 255) / 256, 256, 0, stream>>>(W_author, Wta, INDIM, HIDD);
    gemm_bf16_kernel<8, true, false, true><<<(NPER + 63) / 64, 256, 0, stream>>>(
        x_paper, Wtp, INDIM, b_paper, NPER, lat0, lat1, nullptr, HIDD);
    gemm_bf16_kernel<8, true, false, true><<<(NPER + 63) / 64, 256, 0, stream>>>(
        x_author, Wta, INDIM, b_author, NPER,
        lat0 + (size_t)NPER * HIDD, lat1 + (size_t)NPER * HIDD, nullptr, HIDD);

    // ---- CSR over (dst, rel) segments (shared by all 3 convs) ----
    hipMemsetAsync(rowptr, 0, (NSEG + 1) * sizeof(int), stream);
    hist_kernel<<<(NEDGE + 255) / 256, 256, 0, stream>>>(ei, et, rowptr);
    int nchunk = (NSEG + 1 + SCAN_CHUNK - 1) / SCAN_CHUNK;   // 391
    scan1_kernel<<<nchunk, 256, 0, stream>>>(rowptr, NSEG + 1, bsum);
    scan2_kernel<<<1, 512, 0, stream>>>(bsum, nchunk);
    scan3_kernel<<<nchunk, 256, 0, stream>>>(rowptr, NSEG + 1, bsum);
    hipMemcpyAsync(fill, rowptr, NSEG * sizeof(int), hipMemcpyDeviceToDevice, stream);
    scatter_kernel<<<(NEDGE + 255) / 256, 256, 0, stream>>>(ei, et, fill, esrc);

    // ---- conv0: x1 = relu(rgcn(x0)) -> lat2 ----
    build_wt_conv_kernel<<<(640 * HIDD + 255) / 256, 256, 0, stream>>>(bases0, root0, HIDD, Wt);
    agg_kernel<<<NNODE / 4, 256, 0, stream>>>(lat0, comp0, rowptr, esrc, Abuf);
    gemm_bf16_kernel<8, true, false, false><<<(NNODE + 63) / 64, 256, 0, stream>>>(
        Abuf, Wt, 640, bias0, NNODE, lat2, nullptr, nullptr, HIDD);

    // ---- conv1: x2 = x1 + relu(rgcn(x1)) ----
    build_wt_conv_kernel<<<(640 * HIDD + 255) / 256, 256, 0, stream>>>(bases1, root1, HIDD, Wt);
    agg_kernel<<<NNODE / 4, 256, 0, stream>>>(lat2, comp1, rowptr, esrc, Abuf);
    gemm_bf16_kernel<8, true, true, false><<<(NNODE + 63) / 64, 256, 0, stream>>>(
        Abuf, Wt, 640, bias1, NNODE, x2, nullptr, lat2, HIDD);

    // ---- conv2: out = rgcn(x2) (no relu) ----
    build_wt_conv_kernel<<<(640 * OUTD + 255) / 256, 256, 0, stream>>>(bases2, root2, OUTD, Wt);
    agg_kernel<<<NNODE / 4, 256, 0, stream>>>(x2, comp2, rowptr, esrc, Abuf);
    gemm_bf16_kernel<4, false, false, false><<<(NNODE + 63) / 64, 256, 0, stream>>>(
        Abuf, Wt, 640, bias2, NNODE, outF, nullptr, nullptr, OUTD);
}

// Round 3
// 621.938 us; speedup vs baseline: 1.2276x; 1.2276x over previous
//
#include <hip/hip_runtime.h>
#include <stdint.h>

#define NPER  25000
#define NNODE 50000
#define NEDGE 600000
#define NREL  8
#define NBASE 4
#define INDIM 256
#define HIDD  128
#define OUTD  64
#define NSEG  (NNODE * NREL)

typedef unsigned short u16;
typedef unsigned int   u32;
typedef __attribute__((ext_vector_type(8))) __bf16          bf16x8;
typedef __attribute__((ext_vector_type(8))) unsigned short  ushort8;
typedef __attribute__((ext_vector_type(4))) float           f32x4;
typedef __attribute__((ext_vector_type(2))) float           f32x2;

__device__ __forceinline__ u16 f2b(float f) {
    union { __bf16 h; u16 u; } v; v.h = (__bf16)f; return v.u;   // HW RNE cvt
}
__device__ __forceinline__ bf16x8 as_bf(ushort8 u) {
    union { ushort8 a; bf16x8 b; } v; v.a = u; return v.b;
}
__device__ __forceinline__ bf16x8 cvt8(const float* p) {
    f32x4 f0 = *(const f32x4*)p;
    f32x4 f1 = *(const f32x4*)(p + 4);
    ushort8 u;
#pragma unroll
    for (int i = 0; i < 4; i++) { u[i] = f2b(f0[i]); u[i + 4] = f2b(f1[i]); }
    return as_bf(u);
}

// ---------------- weight repack: fp32 W[k][col] -> bf16 MFMA-fragment-swizzled ------
// Bsw[((ks*NT + nt) << 9) + lane*8 + j] = W[k][col],
//   k = ks*32 + (lane>>4)*8 + j, col = nt*16 + (lane&15).
// Each GEMM B-load becomes one contiguous 1KB wave transaction.

// proj: W is [K][128] row-major (W_paper/W_author), ncol=128
__global__ void build_bsw_proj(const float* __restrict__ W, int K, u16* __restrict__ Bsw) {
    int idx = blockIdx.x * blockDim.x + threadIdx.x;
    if (idx >= K * 128) return;
    int j    = idx & 7;
    int lane = (idx >> 3) & 63;
    int rest = idx >> 9;
    int nt   = rest & 7;           // 128/16 = 8 col tiles
    int ks   = rest >> 3;
    int col  = nt * 16 + (lane & 15);
    int k    = ks * 32 + ((lane >> 4) << 3) + j;
    Bsw[idx] = f2b(W[(size_t)k * 128 + col]);
}

// conv: virtual W1[k][col]: k<512 -> bases[(k)*ncol+col] (bases is [512][ncol] flat),
//       k>=512 -> root[(k-512)*ncol+col].  K=640 fixed.
__global__ void build_bsw_conv(const float* __restrict__ bases, const float* __restrict__ root,
                               int ncol, u16* __restrict__ Bsw) {
    int idx = blockIdx.x * blockDim.x + threadIdx.x;
    if (idx >= 640 * ncol) return;
    int nt_cnt = ncol >> 4;
    int j    = idx & 7;
    int lane = (idx >> 3) & 63;
    int rest = idx >> 9;
    int nt   = rest % nt_cnt;
    int ks   = rest / nt_cnt;
    int col  = nt * 16 + (lane & 15);
    int k    = ks * 32 + ((lane >> 4) << 3) + j;
    float v = (k < 512) ? bases[(size_t)k * ncol + col] : root[(size_t)(k - 512) * ncol + col];
    Bsw[idx] = f2b(v);
}

// ---------------- CSR build over seg = dst*8 + etype ----------------
__global__ void hist_kernel(const int* __restrict__ ei, const int* __restrict__ et,
                            int* __restrict__ cnt) {
    int e = blockIdx.x * blockDim.x + threadIdx.x;
    if (e >= NEDGE) return;
    int dst = ei[NEDGE + e];
    int r   = et[e];
    atomicAdd(&cnt[dst * NREL + r], 1);
}

#define SCAN_CHUNK 1024
__global__ void scan1_kernel(int* __restrict__ data, int n, int* __restrict__ bsum) {
    __shared__ int sh[256];
    int t = threadIdx.x;
    int base = blockIdx.x * SCAN_CHUNK + t * 4;
    int v[4];
#pragma unroll
    for (int i = 0; i < 4; i++) v[i] = (base + i < n) ? data[base + i] : 0;
    int tot = v[0] + v[1] + v[2] + v[3];
    sh[t] = tot; __syncthreads();
    for (int off = 1; off < 256; off <<= 1) {
        int x = (t >= off) ? sh[t - off] : 0;
        __syncthreads();
        sh[t] += x;
        __syncthreads();
    }
    int excl = sh[t] - tot;
    if (t == 255) bsum[blockIdx.x] = sh[255];
    int run = excl;
#pragma unroll
    for (int i = 0; i < 4; i++) {
        if (base + i < n) data[base + i] = run;
        run += v[i];
    }
}

__global__ void scan2_kernel(int* __restrict__ bsum, int nb) {
    __shared__ int sh[512];
    int t = threadIdx.x;
    int v = (t < nb) ? bsum[t] : 0;
    sh[t] = v; __syncthreads();
    for (int off = 1; off < 512; off <<= 1) {
        int x = (t >= off) ? sh[t - off] : 0;
        __syncthreads();
        sh[t] += x;
        __syncthreads();
    }
    if (t < nb) bsum[t] = sh[t] - v;
}

__global__ void scan3_kernel(int* __restrict__ data, int n, const int* __restrict__ bsum) {
    int add = bsum[blockIdx.x];
    int base = blockIdx.x * SCAN_CHUNK + threadIdx.x * 4;
#pragma unroll
    for (int i = 0; i < 4; i++)
        if (base + i < n) data[base + i] += add;
}

__global__ void scatter_kernel(const int* __restrict__ ei, const int* __restrict__ et,
                               int* __restrict__ fill, int* __restrict__ esrc) {
    int e = blockIdx.x * blockDim.x + threadIdx.x;
    if (e >= NEDGE) return;
    int src = ei[e];
    int dst = ei[NEDGE + e];
    int r   = et[e];
    int pos = atomicAdd(&fill[dst * NREL + r], 1);
    esrc[pos] = src;
}

// ---------------- fused mean-aggregate + comp contraction ----------------
// One wave per node; lane handles channels (2*lane, 2*lane+1). x is fp32.
// Writes Abuf[node][0:512] = agg2 (b-major, bf16), Abuf[node][512:640] = x[node] (bf16).
__global__ __launch_bounds__(256) void agg_kernel(
    const float* __restrict__ x, const float* __restrict__ comp,
    const int* __restrict__ rowptr, const int* __restrict__ esrc,
    u16* __restrict__ Abuf) {
    int tid  = threadIdx.x;
    int lane = tid & 63;
    int node = blockIdx.x * 4 + (tid >> 6);
    int c0   = lane * 2;
    float a0[NBASE] = {0.f, 0.f, 0.f, 0.f};
    float a1[NBASE] = {0.f, 0.f, 0.f, 0.f};
    int segbase = node * NREL;
#pragma unroll
    for (int r = 0; r < NREL; r++) {
        int s  = rowptr[segbase + r];
        int e_ = rowptr[segbase + r + 1];
        float s0 = 0.f, s1 = 0.f;
        for (int p = s; p < e_; p++) {
            int sn = esrc[p];
            f32x2 u = *(const f32x2*)(x + (size_t)sn * HIDD + c0);
            s0 += u[0];
            s1 += u[1];
        }
        int cnt = e_ - s;
        if (cnt > 0) { float nr = 1.f / (float)cnt; s0 *= nr; s1 *= nr; }
#pragma unroll
        for (int b = 0; b < NBASE; b++) {
            float cb = comp[r * NBASE + b];
            a0[b] += cb * s0;
            a1[b] += cb * s1;
        }
    }
    size_t obase = (size_t)node * 640;
#pragma unroll
    for (int b = 0; b < NBASE; b++) {
        u32 pk = (u32)f2b(a0[b]) | ((u32)f2b(a1[b]) << 16);
        *(u32*)(Abuf + obase + b * HIDD + c0) = pk;
    }
    f32x2 xv = *(const f32x2*)(x + (size_t)node * HIDD + c0);
    *(u32*)(Abuf + obase + 512 + c0) = (u32)f2b(xv[0]) | ((u32)f2b(xv[1]) << 16);
}

// ---------------- MFMA bf16 GEMM: out = epilogue(A[M,KK] @ W + bias), fp32 out ------
// A fp32 row-major (AF32) or bf16 row-major. Bsw is fragment-swizzled (see above).
// Compile-time KK -> fully unrolled, compiler-pipelined K loop (no barriers at all).
template<int KK, int NT, bool RELU, bool RES, bool AF32>
__global__ __launch_bounds__(256) void gemm_bf16_kernel(
    const void* __restrict__ Av, const u16* __restrict__ Bsw,
    const float* __restrict__ bias, int M,
    float* __restrict__ out1, float* __restrict__ out2,
    const float* __restrict__ resid, int ldo) {
    int tid  = threadIdx.x;
    int wave = tid >> 6, lane = tid & 63;
    int l15  = lane & 15, quad = lane >> 4;
    int rowA = blockIdx.x * 64 + wave * 16 + l15;
    if (rowA > M - 1) rowA = M - 1;
    const u16* bp = Bsw + lane * 8;
    f32x4 acc[NT];
#pragma unroll
    for (int i = 0; i < NT; i++) acc[i] = (f32x4){0.f, 0.f, 0.f, 0.f};
#pragma unroll
    for (int ks = 0; ks < KK / 32; ks++) {
        bf16x8 a;
        if (AF32) {
            a = cvt8((const float*)Av + (size_t)rowA * KK + ks * 32 + quad * 8);
        } else {
            a = as_bf(*(const ushort8*)((const u16*)Av + (size_t)rowA * KK + ks * 32 + quad * 8));
        }
#pragma unroll
        for (int nt = 0; nt < NT; nt++) {
            bf16x8 b = as_bf(*(const ushort8*)(bp + ((size_t)(ks * NT + nt) << 9)));
            acc[nt] = __builtin_amdgcn_mfma_f32_16x16x32_bf16(a, b, acc[nt], 0, 0, 0);
        }
    }
    int orow0 = blockIdx.x * 64 + wave * 16 + quad * 4;
#pragma unroll
    for (int r = 0; r < 4; r++) {
        int orow = orow0 + r;
        if (orow < M) {
#pragma unroll
            for (int nt = 0; nt < NT; nt++) {
                int col = nt * 16 + l15;
                float v = acc[nt][r] + bias[col];
                if (RELU) v = v > 0.f ? v : 0.f;
                if (RES)  v += resid[(size_t)orow * ldo + col];
                out1[(size_t)orow * ldo + col] = v;
                if (out2) out2[(size_t)orow * ldo + col] = v;
            }
        }
    }
}

extern "C" void kernel_launch(void* const* d_in, const int* in_sizes, int n_in,
                              void* d_out, int out_size, void* d_ws, size_t ws_size,
                              hipStream_t stream) {
    const float* x_paper  = (const float*)d_in[0];
    const float* x_author = (const float*)d_in[1];
    const float* W_paper  = (const float*)d_in[2];
    const float* b_paper  = (const float*)d_in[3];
    const float* W_author = (const float*)d_in[4];
    const float* b_author = (const float*)d_in[5];
    const float* bases0   = (const float*)d_in[6];
    const float* comp0    = (const float*)d_in[7];
    const float* root0    = (const float*)d_in[8];
    const float* bias0    = (const float*)d_in[9];
    const float* bases1   = (const float*)d_in[10];
    const float* comp1    = (const float*)d_in[11];
    const float* root1    = (const float*)d_in[12];
    const float* bias1    = (const float*)d_in[13];
    const float* bases2   = (const float*)d_in[14];
    const float* comp2    = (const float*)d_in[15];
    const float* root2    = (const float*)d_in[16];
    const float* bias2    = (const float*)d_in[17];
    const int* ei         = (const int*)d_in[18];
    const int* et         = (const int*)d_in[19];

    float* ob   = (float*)d_out;
    float* outF = ob;                         // [50000,64]
    float* lat0 = ob + 3200000;               // x0
    float* lat1 = ob + 9600000;               // x0 (copy)
    float* lat2 = ob + 16000000;              // x1

    char* w = (char*)d_ws;
    u16*   Abuf   = (u16*)(w + 0);            // 50000*640*2  = 64,000,000
    float* x2     = (float*)(w + 64000000);   // 50000*128*4  = 25,600,000
    u16*   Bswc   = (u16*)(w + 89600000);     // 640*128*2    =    163,840
    u16*   Bswp   = (u16*)(w + 89763840);     // 256*128*2    =     65,536
    u16*   Bswa   = (u16*)(w + 89829376);     // 256*128*2    =     65,536
    int*   rowptr = (int*)(w + 89894912);     // 400001*4
    int*   fill   = (int*)(w + 91495168);     // 400000*4
    int*   esrc   = (int*)(w + 93095168);     // 600000*4
    int*   bsum   = (int*)(w + 95495168);     // 512*4

    // ---- projections: x0 = relu(x @ W + b), written to both latent copies ----
    build_bsw_proj<<<(INDIM * HIDD + 255) / 256, 256, 0, stream>>>(W_paper, INDIM, Bswp);
    build_bsw_proj<<<(INDIM * HIDD + 255) / 256, 256, 0, stream>>>(W_author, INDIM, Bswa);
    gemm_bf16_kernel<256, 8, true, false, true><<<(NPER + 63) / 64, 256, 0, stream>>>(
        x_paper, Bswp, b_paper, NPER, lat0, lat1, nullptr, HIDD);
    gemm_bf16_kernel<256, 8, true, false, true><<<(NPER + 63) / 64, 256, 0, stream>>>(
        x_author, Bswa, b_author, NPER,
        lat0 + (size_t)NPER * HIDD, lat1 + (size_t)NPER * HIDD, nullptr, HIDD);

    // ---- CSR over (dst, rel) segments (shared by all 3 convs) ----
    hipMemsetAsync(rowptr, 0, (NSEG + 1) * sizeof(int), stream);
    hist_kernel<<<(NEDGE + 255) / 256, 256, 0, stream>>>(ei, et, rowptr);
    int nchunk = (NSEG + 1 + SCAN_CHUNK - 1) / SCAN_CHUNK;   // 391
    scan1_kernel<<<nchunk, 256, 0, stream>>>(rowptr, NSEG + 1, bsum);
    scan2_kernel<<<1, 512, 0, stream>>>(bsum, nchunk);
    scan3_kernel<<<nchunk, 256, 0, stream>>>(rowptr, NSEG + 1, bsum);
    hipMemcpyAsync(fill, rowptr, NSEG * sizeof(int), hipMemcpyDeviceToDevice, stream);
    scatter_kernel<<<(NEDGE + 255) / 256, 256, 0, stream>>>(ei, et, fill, esrc);

    // ---- conv0: x1 = relu(rgcn(x0)) -> lat2 ----
    build_bsw_conv<<<(640 * HIDD + 255) / 256, 256, 0, stream>>>(bases0, root0, HIDD, Bswc);
    agg_kernel<<<NNODE / 4, 256, 0, stream>>>(lat0, comp0, rowptr, esrc, Abuf);
    gemm_bf16_kernel<640, 8, true, false, false><<<(NNODE + 63) / 64, 256, 0, stream>>>(
        Abuf, Bswc, bias0, NNODE, lat2, nullptr, nullptr, HIDD);

    // ---- conv1: x2 = x1 + relu(rgcn(x1)) ----
    build_bsw_conv<<<(640 * HIDD + 255) / 256, 256, 0, stream>>>(bases1, root1, HIDD, Bswc);
    agg_kernel<<<NNODE / 4, 256, 0, stream>>>(lat2, comp1, rowptr, esrc, Abuf);
    gemm_bf16_kernel<640, 8, true, true, false><<<(NNODE + 63) / 64, 256, 0, stream>>>(
        Abuf, Bswc, bias1, NNODE, x2, nullptr, lat2, HIDD);

    // ---- conv2: out = rgcn(x2) (no relu) ----
    build_bsw_conv<<<(640 * OUTD + 255) / 256, 256, 0, stream>>>(bases2, root2, OUTD, Bswc);
    agg_kernel<<<NNODE / 4, 256, 0, stream>>>(x2, comp2, rowptr, esrc, Abuf);
    gemm_bf16_kernel<640, 4, false, false, false><<<(NNODE + 63) / 64, 256, 0, stream>>>(
        Abuf, Bswc, bias2, NNODE, outF, nullptr, nullptr, OUTD);
}

// Round 4
// 465.787 us; speedup vs baseline: 1.6391x; 1.3352x over previous
//
#include <hip/hip_runtime.h>
#include <stdint.h>

#define NPER  25000
#define NNODE 50000
#define NEDGE 600000
#define NREL  8
#define NBASE 4
#define INDIM 256
#define HIDD  128
#define OUTD  64
#define NSEG  (NNODE * NREL)

typedef unsigned short u16;
typedef unsigned int   u32;
typedef __attribute__((ext_vector_type(8))) __bf16          bf16x8;
typedef __attribute__((ext_vector_type(8))) unsigned short  ushort8;
typedef __attribute__((ext_vector_type(4))) float           f32x4;

__device__ __forceinline__ u16 f2b(float f) {
    union { __bf16 h; u16 u; } v; v.h = (__bf16)f; return v.u;   // HW RNE cvt
}
__device__ __forceinline__ bf16x8 as_bf(ushort8 u) {
    union { ushort8 a; bf16x8 b; } v; v.a = u; return v.b;
}
__device__ __forceinline__ bf16x8 cvt8(const float* p) {
    f32x4 f0 = *(const f32x4*)p;
    f32x4 f1 = *(const f32x4*)(p + 4);
    ushort8 u;
#pragma unroll
    for (int i = 0; i < 4; i++) { u[i] = f2b(f0[i]); u[i + 4] = f2b(f1[i]); }
    return as_bf(u);
}
__device__ __forceinline__ float blo(u32 v) {
    union { u32 i; float f; } u; u.i = v << 16; return u.f;
}
__device__ __forceinline__ float bhi(u32 v) {
    union { u32 i; float f; } u; u.i = v & 0xffff0000u; return u.f;
}

// ---------------- weight repack: fp32 W[k][col] -> bf16 MFMA-fragment-swizzled ------
// Bsw[((ks*NT + nt) << 9) + lane*8 + j] = W[k][col],
//   k = ks*32 + (lane>>4)*8 + j, col = nt*16 + (lane&15).
__global__ void build_bsw_proj(const float* __restrict__ W, int K, u16* __restrict__ Bsw) {
    int idx = blockIdx.x * blockDim.x + threadIdx.x;
    if (idx >= K * 128) return;
    int j    = idx & 7;
    int lane = (idx >> 3) & 63;
    int rest = idx >> 9;
    int nt   = rest & 7;           // 128/16 = 8 col tiles
    int ks   = rest >> 3;
    int col  = nt * 16 + (lane & 15);
    int k    = ks * 32 + ((lane >> 4) << 3) + j;
    Bsw[idx] = f2b(W[(size_t)k * 128 + col]);
}

// conv virtual W1[k][col]: k<512 -> bases[k*ncol+col], k>=512 -> root[(k-512)*ncol+col]. K=640.
__global__ void build_bsw_conv(const float* __restrict__ bases, const float* __restrict__ root,
                               int ncol, u16* __restrict__ Bsw) {
    int idx = blockIdx.x * blockDim.x + threadIdx.x;
    if (idx >= 640 * ncol) return;
    int nt_cnt = ncol >> 4;
    int j    = idx & 7;
    int lane = (idx >> 3) & 63;
    int rest = idx >> 9;
    int nt   = rest % nt_cnt;
    int ks   = rest / nt_cnt;
    int col  = nt * 16 + (lane & 15);
    int k    = ks * 32 + ((lane >> 4) << 3) + j;
    float v = (k < 512) ? bases[(size_t)k * ncol + col] : root[(size_t)(k - 512) * ncol + col];
    Bsw[idx] = f2b(v);
}

// ---------------- CSR build over seg = dst*8 + etype ----------------
__global__ void hist_kernel(const int* __restrict__ ei, const int* __restrict__ et,
                            int* __restrict__ cnt) {
    int e = blockIdx.x * blockDim.x + threadIdx.x;
    if (e >= NEDGE) return;
    int dst = ei[NEDGE + e];
    int r   = et[e];
    atomicAdd(&cnt[dst * NREL + r], 1);
}

#define SCAN_CHUNK 1024
__global__ void scan1_kernel(int* __restrict__ data, int n, int* __restrict__ bsum) {
    __shared__ int sh[256];
    int t = threadIdx.x;
    int base = blockIdx.x * SCAN_CHUNK + t * 4;
    int v[4];
#pragma unroll
    for (int i = 0; i < 4; i++) v[i] = (base + i < n) ? data[base + i] : 0;
    int tot = v[0] + v[1] + v[2] + v[3];
    sh[t] = tot; __syncthreads();
    for (int off = 1; off < 256; off <<= 1) {
        int x = (t >= off) ? sh[t - off] : 0;
        __syncthreads();
        sh[t] += x;
        __syncthreads();
    }
    int excl = sh[t] - tot;
    if (t == 255) bsum[blockIdx.x] = sh[255];
    int run = excl;
#pragma unroll
    for (int i = 0; i < 4; i++) {
        if (base + i < n) data[base + i] = run;
        run += v[i];
    }
}

__global__ void scan2_kernel(int* __restrict__ bsum, int nb) {
    __shared__ int sh[512];
    int t = threadIdx.x;
    int v = (t < nb) ? bsum[t] : 0;
    sh[t] = v; __syncthreads();
    for (int off = 1; off < 512; off <<= 1) {
        int x = (t >= off) ? sh[t - off] : 0;
        __syncthreads();
        sh[t] += x;
        __syncthreads();
    }
    if (t < nb) bsum[t] = sh[t] - v;
}

__global__ void scan3_kernel(int* __restrict__ data, int n, const int* __restrict__ bsum) {
    int add = bsum[blockIdx.x];
    int base = blockIdx.x * SCAN_CHUNK + threadIdx.x * 4;
#pragma unroll
    for (int i = 0; i < 4; i++)
        if (base + i < n) data[base + i] += add;
}

// packs (src | rel<<16) so agg can walk a node's edges as ONE contiguous run
__global__ void scatter_kernel(const int* __restrict__ ei, const int* __restrict__ et,
                               int* __restrict__ fill, int* __restrict__ epk) {
    int e = blockIdx.x * blockDim.x + threadIdx.x;
    if (e >= NEDGE) return;
    int src = ei[e];
    int dst = ei[NEDGE + e];
    int r   = et[e];
    int pos = atomicAdd(&fill[dst * NREL + r], 1);
    epk[pos] = src | (r << 16);
}

// ---------------- fused mean-aggregate + comp contraction ----------------
// One wave per node, single flat edge loop (chunk-4 pipelined). x rows are bf16.
// Per-edge weight w[b] = comp[r][b]/cnt[node,r] via per-wave LDS table.
// Writes Abuf[node][0:512] = agg2 (b-major, bf16). Root part NOT written (GEMM reads xbf).
__global__ __launch_bounds__(256) void agg_kernel(
    const u16* __restrict__ xbf, const float* __restrict__ comp,
    const int* __restrict__ rowptr, const int* __restrict__ epk,
    u16* __restrict__ Abuf) {
    __shared__ float wtab[4][32];
    int tid  = threadIdx.x;
    int wv   = __builtin_amdgcn_readfirstlane(tid >> 6);
    int lane = tid & 63;
    int node = blockIdx.x * 4 + wv;
    int rbase = node * NREL;
    if (lane < 32) {
        int r  = lane >> 2;
        int c0 = rowptr[rbase + r], c1 = rowptr[rbase + r + 1];
        int cnt = c1 - c0;
        float nrm = (cnt > 0) ? 1.f / (float)cnt : 0.f;
        wtab[wv][lane] = comp[lane] * nrm;
    }
    __syncthreads();
    const float* wt = &wtab[wv][0];
    int p = rowptr[rbase];
    int e = rowptr[rbase + 8];
    int co = lane * 2;                      // u16 offset within 128-ch row
    float a0[4] = {0.f, 0.f, 0.f, 0.f};
    float a1[4] = {0.f, 0.f, 0.f, 0.f};
    while (p + 4 <= e) {
        int k0 = epk[p], k1 = epk[p + 1], k2 = epk[p + 2], k3 = epk[p + 3];
        u32 v0 = *(const u32*)(xbf + ((size_t)(k0 & 0xffff) << 7) + co);
        u32 v1 = *(const u32*)(xbf + ((size_t)(k1 & 0xffff) << 7) + co);
        u32 v2 = *(const u32*)(xbf + ((size_t)(k2 & 0xffff) << 7) + co);
        u32 v3 = *(const u32*)(xbf + ((size_t)(k3 & 0xffff) << 7) + co);
        f32x4 w0 = *(const f32x4*)(wt + ((k0 >> 16) << 2));
        f32x4 w1 = *(const f32x4*)(wt + ((k1 >> 16) << 2));
        f32x4 w2 = *(const f32x4*)(wt + ((k2 >> 16) << 2));
        f32x4 w3 = *(const f32x4*)(wt + ((k3 >> 16) << 2));
        float x00 = blo(v0), x01 = bhi(v0);
        float x10 = blo(v1), x11 = bhi(v1);
        float x20 = blo(v2), x21 = bhi(v2);
        float x30 = blo(v3), x31 = bhi(v3);
#pragma unroll
        for (int b = 0; b < 4; b++) {
            a0[b] += w0[b] * x00; a1[b] += w0[b] * x01;
            a0[b] += w1[b] * x10; a1[b] += w1[b] * x11;
            a0[b] += w2[b] * x20; a1[b] += w2[b] * x21;
            a0[b] += w3[b] * x30; a1[b] += w3[b] * x31;
        }
        p += 4;
    }
    while (p < e) {
        int k0 = epk[p];
        u32 v0 = *(const u32*)(xbf + ((size_t)(k0 & 0xffff) << 7) + co);
        f32x4 w0 = *(const f32x4*)(wt + ((k0 >> 16) << 2));
        float x00 = blo(v0), x01 = bhi(v0);
#pragma unroll
        for (int b = 0; b < 4; b++) { a0[b] += w0[b] * x00; a1[b] += w0[b] * x01; }
        p++;
    }
    size_t ob = (size_t)node * 512 + co;
#pragma unroll
    for (int b = 0; b < 4; b++) {
        u32 pk = (u32)f2b(a0[b]) | ((u32)f2b(a1[b]) << 16);
        *(u32*)(Abuf + ob + b * 128) = pk;
    }
}

// ---------------- MFMA bf16 GEMM ----------------
// A = [M,KMAIN] (fp32 if AF32 else bf16) plus optional [M,128] bf16 tail (HASX: xq).
// Bsw fragment-swizzled over full K = KMAIN + (HASX?128:0). Fully unrolled K loop.
// Epilogue: v = (relu?)(acc+bias) (+resid); stores to out1/out2 (fp32) and outb (bf16), each optional.
template<int KMAIN, bool HASX, int NT, bool RELU, bool RES, bool AF32>
__global__ __launch_bounds__(256) void gemm_kernel(
    const void* __restrict__ Av, const u16* __restrict__ xq,
    const u16* __restrict__ Bsw, const float* __restrict__ bias, int M,
    float* __restrict__ out1, float* __restrict__ out2, u16* __restrict__ outb,
    const float* __restrict__ resid, int ldo) {
    constexpr int KSM = KMAIN / 32;
    constexpr int KST = KSM + (HASX ? 4 : 0);
    int tid  = threadIdx.x;
    int wave = tid >> 6, lane = tid & 63;
    int l15  = lane & 15, quad = lane >> 4;
    int rowA = blockIdx.x * 64 + wave * 16 + l15;
    if (rowA > M - 1) rowA = M - 1;
    const u16* bp = Bsw + lane * 8;
    f32x4 acc[NT];
#pragma unroll
    for (int i = 0; i < NT; i++) acc[i] = (f32x4){0.f, 0.f, 0.f, 0.f};
#pragma unroll
    for (int ks = 0; ks < KST; ks++) {
        bf16x8 a;
        if (ks < KSM) {
            if (AF32) a = cvt8((const float*)Av + (size_t)rowA * KMAIN + ks * 32 + quad * 8);
            else      a = as_bf(*(const ushort8*)((const u16*)Av + (size_t)rowA * KMAIN + ks * 32 + quad * 8));
        } else {
            a = as_bf(*(const ushort8*)(xq + (size_t)rowA * 128 + (ks - KSM) * 32 + quad * 8));
        }
#pragma unroll
        for (int nt = 0; nt < NT; nt++) {
            bf16x8 b = as_bf(*(const ushort8*)(bp + ((size_t)(ks * NT + nt) << 9)));
            acc[nt] = __builtin_amdgcn_mfma_f32_16x16x32_bf16(a, b, acc[nt], 0, 0, 0);
        }
    }
    int orow0 = blockIdx.x * 64 + wave * 16 + quad * 4;
#pragma unroll
    for (int r = 0; r < 4; r++) {
        int orow = orow0 + r;
        if (orow < M) {
#pragma unroll
            for (int nt = 0; nt < NT; nt++) {
                int col = nt * 16 + l15;
                float v = acc[nt][r] + bias[col];
                if (RELU) v = v > 0.f ? v : 0.f;
                if (RES)  v += resid[(size_t)orow * ldo + col];
                size_t oi = (size_t)orow * ldo + col;
                if (out1) out1[oi] = v;
                if (out2) out2[oi] = v;
                if (outb) outb[oi] = f2b(v);
            }
        }
    }
}

extern "C" void kernel_launch(void* const* d_in, const int* in_sizes, int n_in,
                              void* d_out, int out_size, void* d_ws, size_t ws_size,
                              hipStream_t stream) {
    const float* x_paper  = (const float*)d_in[0];
    const float* x_author = (const float*)d_in[1];
    const float* W_paper  = (const float*)d_in[2];
    const float* b_paper  = (const float*)d_in[3];
    const float* W_author = (const float*)d_in[4];
    const float* b_author = (const float*)d_in[5];
    const float* bases0   = (const float*)d_in[6];
    const float* comp0    = (const float*)d_in[7];
    const float* root0    = (const float*)d_in[8];
    const float* bias0    = (const float*)d_in[9];
    const float* bases1   = (const float*)d_in[10];
    const float* comp1    = (const float*)d_in[11];
    const float* root1    = (const float*)d_in[12];
    const float* bias1    = (const float*)d_in[13];
    const float* bases2   = (const float*)d_in[14];
    const float* comp2    = (const float*)d_in[15];
    const float* root2    = (const float*)d_in[16];
    const float* bias2    = (const float*)d_in[17];
    const int* ei         = (const int*)d_in[18];
    const int* et         = (const int*)d_in[19];

    float* ob   = (float*)d_out;
    float* outF = ob;                         // [50000,64]
    float* lat0 = ob + 3200000;               // x0
    float* lat1 = ob + 9600000;               // x0 (copy)
    float* lat2 = ob + 16000000;              // x1

    char* w = (char*)d_ws;
    u16*   Abuf   = (u16*)(w + 0);            // 50000*512*2 = 51,200,000
    u16*   xbf0   = (u16*)(w + 51200000);     // 50000*128*2 = 12,800,000
    u16*   xbf1   = (u16*)(w + 64000000);     // 12,800,000
    u16*   Bswc   = (u16*)(w + 76800000);     // 163,840
    u16*   Bswp   = (u16*)(w + 76963840);     // 65,536
    u16*   Bswa   = (u16*)(w + 77029376);     // 65,536
    int*   rowptr = (int*)(w + 77094912);     // 400001*4 (pad to 1,600,064)
    int*   fill   = (int*)(w + 78694976);     // 1,600,000
    int*   epk    = (int*)(w + 80294976);     // 2,400,000
    int*   bsum   = (int*)(w + 82694976);     // 2,048

    // ---- projections: x0 = relu(x @ W + b) -> lat0, lat1 (fp32) + xbf0 (bf16) ----
    build_bsw_proj<<<(INDIM * HIDD + 255) / 256, 256, 0, stream>>>(W_paper, INDIM, Bswp);
    build_bsw_proj<<<(INDIM * HIDD + 255) / 256, 256, 0, stream>>>(W_author, INDIM, Bswa);
    gemm_kernel<256, false, 8, true, false, true><<<(NPER + 63) / 64, 256, 0, stream>>>(
        x_paper, nullptr, Bswp, b_paper, NPER, lat0, lat1, xbf0, nullptr, HIDD);
    gemm_kernel<256, false, 8, true, false, true><<<(NPER + 63) / 64, 256, 0, stream>>>(
        x_author, nullptr, Bswa, b_author, NPER,
        lat0 + (size_t)NPER * HIDD, lat1 + (size_t)NPER * HIDD,
        xbf0 + (size_t)NPER * HIDD, nullptr, HIDD);

    // ---- CSR over (dst, rel) segments (shared by all 3 convs) ----
    hipMemsetAsync(rowptr, 0, (NSEG + 1) * sizeof(int), stream);
    hist_kernel<<<(NEDGE + 255) / 256, 256, 0, stream>>>(ei, et, rowptr);
    int nchunk = (NSEG + 1 + SCAN_CHUNK - 1) / SCAN_CHUNK;   // 391
    scan1_kernel<<<nchunk, 256, 0, stream>>>(rowptr, NSEG + 1, bsum);
    scan2_kernel<<<1, 512, 0, stream>>>(bsum, nchunk);
    scan3_kernel<<<nchunk, 256, 0, stream>>>(rowptr, NSEG + 1, bsum);
    hipMemcpyAsync(fill, rowptr, NSEG * sizeof(int), hipMemcpyDeviceToDevice, stream);
    scatter_kernel<<<(NEDGE + 255) / 256, 256, 0, stream>>>(ei, et, fill, epk);

    // ---- conv0: x1 = relu(rgcn(x0)) -> lat2 (fp32) + xbf1 (bf16) ----
    build_bsw_conv<<<(640 * HIDD + 255) / 256, 256, 0, stream>>>(bases0, root0, HIDD, Bswc);
    agg_kernel<<<NNODE / 4, 256, 0, stream>>>(xbf0, comp0, rowptr, epk, Abuf);
    gemm_kernel<512, true, 8, true, false, false><<<(NNODE + 63) / 64, 256, 0, stream>>>(
        Abuf, xbf0, Bswc, bias0, NNODE, lat2, nullptr, xbf1, nullptr, HIDD);

    // ---- conv1: x2 = x1 + relu(rgcn(x1)) -> xbf0 (bf16 only; x2 not an output) ----
    build_bsw_conv<<<(640 * HIDD + 255) / 256, 256, 0, stream>>>(bases1, root1, HIDD, Bswc);
    agg_kernel<<<NNODE / 4, 256, 0, stream>>>(xbf1, comp1, rowptr, epk, Abuf);
    gemm_kernel<512, true, 8, true, true, false><<<(NNODE + 63) / 64, 256, 0, stream>>>(
        Abuf, xbf1, Bswc, bias1, NNODE, nullptr, nullptr, xbf0, lat2, HIDD);

    // ---- conv2: out = rgcn(x2) (no relu) -> outF fp32 ----
    build_bsw_conv<<<(640 * OUTD + 255) / 256, 256, 0, stream>>>(bases2, root2, OUTD, Bswc);
    agg_kernel<<<NNODE / 4, 256, 0, stream>>>(xbf0, comp2, rowptr, epk, Abuf);
    gemm_kernel<512, true, 4, false, false, false><<<(NNODE + 63) / 64, 256, 0, stream>>>(
        Abuf, xbf0, Bswc, bias2, NNODE, outF, nullptr, nullptr, nullptr, OUTD);
}

// Round 5
// 454.994 us; speedup vs baseline: 1.6780x; 1.0237x over previous
//
#include <hip/hip_runtime.h>
#include <stdint.h>

#define NPER  25000
#define NNODE 50000
#define NEDGE 600000
#define NREL  8
#define NBASE 4
#define INDIM 256
#define HIDD  128
#define OUTD  64
#define NSEG  (NNODE * NREL)

typedef unsigned short u16;
typedef unsigned int   u32;
typedef __attribute__((ext_vector_type(8))) __bf16          bf16x8;
typedef __attribute__((ext_vector_type(8))) unsigned short  ushort8;
typedef __attribute__((ext_vector_type(4))) float           f32x4;

__device__ __forceinline__ u16 f2b(float f) {
    union { __bf16 h; u16 u; } v; v.h = (__bf16)f; return v.u;   // HW RNE cvt
}
__device__ __forceinline__ bf16x8 as_bf(ushort8 u) {
    union { ushort8 a; bf16x8 b; } v; v.a = u; return v.b;
}
__device__ __forceinline__ bf16x8 cvt8(const float* p) {
    f32x4 f0 = *(const f32x4*)p;
    f32x4 f1 = *(const f32x4*)(p + 4);
    ushort8 u;
#pragma unroll
    for (int i = 0; i < 4; i++) { u[i] = f2b(f0[i]); u[i + 4] = f2b(f1[i]); }
    return as_bf(u);
}
__device__ __forceinline__ float blo(u32 v) {
    union { u32 i; float f; } u; u.i = v << 16; return u.f;
}
__device__ __forceinline__ float bhi(u32 v) {
    union { u32 i; float f; } u; u.i = v & 0xffff0000u; return u.f;
}

// ---------------- fused weight repack: all 5 Bsw buffers in ONE kernel ----------------
// Bsw[((ks*NT + nt) << 9) + lane*8 + j] = W[k][col],
//   k = ks*32 + (lane>>4)*8 + j, col = nt*16 + (lane&15).
__device__ __forceinline__ void bsw_proj_elem(const float* __restrict__ W, u16* __restrict__ out, int idx) {
    int j    = idx & 7;
    int lane = (idx >> 3) & 63;
    int rest = idx >> 9;
    int nt   = rest & 7;           // 128/16 = 8 col tiles
    int ks   = rest >> 3;
    int col  = nt * 16 + (lane & 15);
    int k    = ks * 32 + ((lane >> 4) << 3) + j;
    out[idx] = f2b(W[(size_t)k * 128 + col]);
}
__device__ __forceinline__ void bsw_conv_elem(const float* __restrict__ bases, const float* __restrict__ root,
                                              int ncol, u16* __restrict__ out, int idx) {
    int nt_cnt = ncol >> 4;
    int j    = idx & 7;
    int lane = (idx >> 3) & 63;
    int rest = idx >> 9;
    int nt   = rest % nt_cnt;
    int ks   = rest / nt_cnt;
    int col  = nt * 16 + (lane & 15);
    int k    = ks * 32 + ((lane >> 4) << 3) + j;
    float v = (k < 512) ? bases[(size_t)k * ncol + col] : root[(size_t)(k - 512) * ncol + col];
    out[idx] = f2b(v);
}
// block ranges: [0,128) Wp | [128,256) Wa | [256,576) conv0 | [576,896) conv1 | [896,1056) conv2
__global__ void build_bsw_all(const float* __restrict__ Wp, const float* __restrict__ Wa,
                              const float* __restrict__ bases0, const float* __restrict__ root0,
                              const float* __restrict__ bases1, const float* __restrict__ root1,
                              const float* __restrict__ bases2, const float* __restrict__ root2,
                              u16* __restrict__ Bswp, u16* __restrict__ Bswa,
                              u16* __restrict__ Bswc0, u16* __restrict__ Bswc1, u16* __restrict__ Bswc2) {
    int b = blockIdx.x, t = threadIdx.x;
    if (b < 128)       bsw_proj_elem(Wp, Bswp, b * 256 + t);
    else if (b < 256)  bsw_proj_elem(Wa, Bswa, (b - 128) * 256 + t);
    else if (b < 576)  bsw_conv_elem(bases0, root0, HIDD, Bswc0, (b - 256) * 256 + t);
    else if (b < 896)  bsw_conv_elem(bases1, root1, HIDD, Bswc1, (b - 576) * 256 + t);
    else               bsw_conv_elem(bases2, root2, OUTD, Bswc2, (b - 896) * 256 + t);
}

// ---------------- CSR build over seg = dst*8 + etype ----------------
__global__ void hist_kernel(const int* __restrict__ ei, const int* __restrict__ et,
                            int* __restrict__ cnt) {
    int e = blockIdx.x * blockDim.x + threadIdx.x;
    if (e >= NEDGE) return;
    int dst = ei[NEDGE + e];
    int r   = et[e];
    atomicAdd(&cnt[dst * NREL + r], 1);
}

#define SCAN_CHUNK 1024
__global__ void scan1_kernel(int* __restrict__ data, int n, int* __restrict__ bsum) {
    __shared__ int sh[256];
    int t = threadIdx.x;
    int base = blockIdx.x * SCAN_CHUNK + t * 4;
    int v[4];
#pragma unroll
    for (int i = 0; i < 4; i++) v[i] = (base + i < n) ? data[base + i] : 0;
    int tot = v[0] + v[1] + v[2] + v[3];
    sh[t] = tot; __syncthreads();
    for (int off = 1; off < 256; off <<= 1) {
        int x = (t >= off) ? sh[t - off] : 0;
        __syncthreads();
        sh[t] += x;
        __syncthreads();
    }
    int excl = sh[t] - tot;
    if (t == 255) bsum[blockIdx.x] = sh[255];
    int run = excl;
#pragma unroll
    for (int i = 0; i < 4; i++) {
        if (base + i < n) data[base + i] = run;
        run += v[i];
    }
}

__global__ void scan2_kernel(int* __restrict__ bsum, int nb) {
    __shared__ int sh[512];
    int t = threadIdx.x;
    int v = (t < nb) ? bsum[t] : 0;
    sh[t] = v; __syncthreads();
    for (int off = 1; off < 512; off <<= 1) {
        int x = (t >= off) ? sh[t - off] : 0;
        __syncthreads();
        sh[t] += x;
        __syncthreads();
    }
    if (t < nb) bsum[t] = sh[t] - v;
}

// also materializes fill[] (scatter cursor) — drops the d2d memcpy dispatch
__global__ void scan3_kernel(int* __restrict__ data, int n, const int* __restrict__ bsum,
                             int* __restrict__ fill) {
    int add = bsum[blockIdx.x];
    int base = blockIdx.x * SCAN_CHUNK + threadIdx.x * 4;
#pragma unroll
    for (int i = 0; i < 4; i++) {
        int idx = base + i;
        if (idx < n) {
            int v = data[idx] + add;
            data[idx] = v;
            if (idx < NSEG) fill[idx] = v;
        }
    }
}

// packs (src | rel<<16) so agg can walk a node's edges as ONE contiguous run
__global__ void scatter_kernel(const int* __restrict__ ei, const int* __restrict__ et,
                               int* __restrict__ fill, int* __restrict__ epk) {
    int e = blockIdx.x * blockDim.x + threadIdx.x;
    if (e >= NEDGE) return;
    int src = ei[e];
    int dst = ei[NEDGE + e];
    int r   = et[e];
    int pos = atomicAdd(&fill[dst * NREL + r], 1);
    epk[pos] = src | (r << 16);
}

// ---------------- fused mean-aggregate + comp contraction ----------------
// One wave per node, flat edge walk, explicit 2-chunk register pipeline with
// sentinel masking (rel=8 -> zero weight slot). x rows are bf16 (2 ch/lane).
__global__ __launch_bounds__(256) void agg_kernel(
    const u16* __restrict__ xbf, const float* __restrict__ comp,
    const int* __restrict__ rowptr, const int* __restrict__ epk,
    u16* __restrict__ Abuf) {
    __shared__ float wtab[4][40];          // [wave][rel*4+b]; rel=8 slots are 0
    int tid  = threadIdx.x;
    int wv   = __builtin_amdgcn_readfirstlane(tid >> 6);
    int lane = tid & 63;
    int node = blockIdx.x * 4 + wv;
    int rbase = node * NREL;
    if (lane < 36) {
        float wval = 0.f;
        if (lane < 32) {
            int r  = lane >> 2;
            int c0 = rowptr[rbase + r], c1 = rowptr[rbase + r + 1];
            int cnt = c1 - c0;
            float nrm = (cnt > 0) ? 1.f / (float)cnt : 0.f;
            wval = comp[lane] * nrm;
        }
        wtab[wv][lane] = wval;
    }
    __syncthreads();
    const float* wt = &wtab[wv][0];
    int p = __builtin_amdgcn_readfirstlane(rowptr[rbase]);
    int e = __builtin_amdgcn_readfirstlane(rowptr[rbase + 8]);
    int co = lane * 2;                     // u16 offset within 128-ch row
    const int INV = 8 << 16;               // sentinel: src=0, rel=8 (zero weight)
    float a0[4] = {0.f, 0.f, 0.f, 0.f};
    float a1[4] = {0.f, 0.f, 0.f, 0.f};
    int k0[4]; u32 v0[4];
#pragma unroll
    for (int i = 0; i < 4; i++) k0[i] = (p + i < e) ? epk[p + i] : INV;
#pragma unroll
    for (int i = 0; i < 4; i++) v0[i] = *(const u32*)(xbf + ((size_t)(k0[i] & 0xffff) << 7) + co);
    for (int pc = p; pc < e; pc += 4) {
        int pn = pc + 4;
        int k1[4]; u32 v1[4];
#pragma unroll
        for (int i = 0; i < 4; i++) k1[i] = (pn + i < e) ? epk[pn + i] : INV;
#pragma unroll
        for (int i = 0; i < 4; i++) v1[i] = *(const u32*)(xbf + ((size_t)(k1[i] & 0xffff) << 7) + co);
#pragma unroll
        for (int i = 0; i < 4; i++) {
            f32x4 w = *(const f32x4*)(wt + ((k0[i] >> 16) << 2));
            float xl = blo(v0[i]), xh = bhi(v0[i]);
#pragma unroll
            for (int b = 0; b < 4; b++) { a0[b] += w[b] * xl; a1[b] += w[b] * xh; }
        }
#pragma unroll
        for (int i = 0; i < 4; i++) { k0[i] = k1[i]; v0[i] = v1[i]; }
    }
    size_t ob = (size_t)node * 512 + co;
#pragma unroll
    for (int b = 0; b < 4; b++) {
        u32 pk = (u32)f2b(a0[b]) | ((u32)f2b(a1[b]) << 16);
        *(u32*)(Abuf + ob + b * 128) = pk;
    }
}

// ---------------- MFMA bf16 GEMM core ----------------
// A = [M,KMAIN] (fp32 if AF32 else bf16) plus optional [M,128] bf16 tail (HASX: xq).
// Bsw fragment-swizzled over full K. MW row-tiles per wave (B frag reused MW times).
template<int KMAIN, bool HASX, int NW, int MW, int NT, bool RELU, bool RES, bool AF32>
__device__ __forceinline__ void gemm_core(
    int blk, const void* __restrict__ Av, const u16* __restrict__ xq,
    const u16* __restrict__ Bsw, const float* __restrict__ bias, int M,
    float* __restrict__ out1, float* __restrict__ out2, u16* __restrict__ outb,
    const float* __restrict__ resid, int ldo) {
    constexpr int KSM = KMAIN / 32;
    constexpr int KST = KSM + (HASX ? 4 : 0);
    int tid  = threadIdx.x;
    int wave = tid >> 6, lane = tid & 63;
    int l15  = lane & 15, quad = lane >> 4;
    int rowbase = blk * (NW * MW * 16) + wave * (MW * 16);
    int rA[MW];
#pragma unroll
    for (int m = 0; m < MW; m++) {
        rA[m] = rowbase + m * 16 + l15;
        if (rA[m] > M - 1) rA[m] = M - 1;
    }
    const u16* bp = Bsw + lane * 8;
    f32x4 acc[MW][NT];
#pragma unroll
    for (int m = 0; m < MW; m++)
#pragma unroll
        for (int i = 0; i < NT; i++) acc[m][i] = (f32x4){0.f, 0.f, 0.f, 0.f};
#pragma unroll
    for (int ks = 0; ks < KST; ks++) {
        bf16x8 a[MW];
#pragma unroll
        for (int m = 0; m < MW; m++) {
            if (ks < KSM) {
                if (AF32) a[m] = cvt8((const float*)Av + (size_t)rA[m] * KMAIN + ks * 32 + quad * 8);
                else      a[m] = as_bf(*(const ushort8*)((const u16*)Av + (size_t)rA[m] * KMAIN + ks * 32 + quad * 8));
            } else {
                a[m] = as_bf(*(const ushort8*)(xq + (size_t)rA[m] * 128 + (ks - KSM) * 32 + quad * 8));
            }
        }
#pragma unroll
        for (int nt = 0; nt < NT; nt++) {
            bf16x8 b = as_bf(*(const ushort8*)(bp + ((size_t)(ks * NT + nt) << 9)));
#pragma unroll
            for (int m = 0; m < MW; m++)
                acc[m][nt] = __builtin_amdgcn_mfma_f32_16x16x32_bf16(a[m], b, acc[m][nt], 0, 0, 0);
        }
    }
#pragma unroll
    for (int m = 0; m < MW; m++) {
        int orow0 = rowbase + m * 16 + quad * 4;
#pragma unroll
        for (int r = 0; r < 4; r++) {
            int orow = orow0 + r;
            if (orow < M) {
#pragma unroll
                for (int nt = 0; nt < NT; nt++) {
                    int col = nt * 16 + l15;
                    float v = acc[m][nt][r] + bias[col];
                    if (RELU) v = v > 0.f ? v : 0.f;
                    if (RES)  v += resid[(size_t)orow * ldo + col];
                    size_t oi = (size_t)orow * ldo + col;
                    if (out1) out1[oi] = v;
                    if (out2) out2[oi] = v;
                    if (outb) outb[oi] = f2b(v);
                }
            }
        }
    }
}

template<int KMAIN, bool HASX, int NW, int MW, int NT, bool RELU, bool RES, bool AF32>
__global__ __launch_bounds__(NW * 64, 2) void gemm_kernel(
    const void* __restrict__ Av, const u16* __restrict__ xq,
    const u16* __restrict__ Bsw, const float* __restrict__ bias, int M,
    float* __restrict__ out1, float* __restrict__ out2, u16* __restrict__ outb,
    const float* __restrict__ resid, int ldo) {
    gemm_core<KMAIN, HASX, NW, MW, NT, RELU, RES, AF32>(
        blockIdx.x, Av, xq, Bsw, bias, M, out1, out2, outb, resid, ldo);
}

// both projections in one dispatch (gridDim.y = 2 selects paper/author)
__global__ __launch_bounds__(256, 2) void proj2_kernel(
    const float* __restrict__ xp, const float* __restrict__ xa,
    const u16* __restrict__ Bswp, const u16* __restrict__ Bswa,
    const float* __restrict__ bp, const float* __restrict__ ba,
    float* __restrict__ lat0, float* __restrict__ lat1, u16* __restrict__ xbf0) {
    int y = blockIdx.y;
    const float* A    = y ? xa : xp;
    const u16*   B    = y ? Bswa : Bswp;
    const float* bias = y ? ba : bp;
    size_t off = (size_t)y * NPER * HIDD;
    gemm_core<256, false, 4, 1, 8, true, false, true>(
        blockIdx.x, A, nullptr, B, bias, NPER, lat0 + off, lat1 + off, xbf0 + off, nullptr, HIDD);
}

extern "C" void kernel_launch(void* const* d_in, const int* in_sizes, int n_in,
                              void* d_out, int out_size, void* d_ws, size_t ws_size,
                              hipStream_t stream) {
    const float* x_paper  = (const float*)d_in[0];
    const float* x_author = (const float*)d_in[1];
    const float* W_paper  = (const float*)d_in[2];
    const float* b_paper  = (const float*)d_in[3];
    const float* W_author = (const float*)d_in[4];
    const float* b_author = (const float*)d_in[5];
    const float* bases0   = (const float*)d_in[6];
    const float* comp0    = (const float*)d_in[7];
    const float* root0    = (const float*)d_in[8];
    const float* bias0    = (const float*)d_in[9];
    const float* bases1   = (const float*)d_in[10];
    const float* comp1    = (const float*)d_in[11];
    const float* root1    = (const float*)d_in[12];
    const float* bias1    = (const float*)d_in[13];
    const float* bases2   = (const float*)d_in[14];
    const float* comp2    = (const float*)d_in[15];
    const float* root2    = (const float*)d_in[16];
    const float* bias2    = (const float*)d_in[17];
    const int* ei         = (const int*)d_in[18];
    const int* et         = (const int*)d_in[19];

    float* ob   = (float*)d_out;
    float* outF = ob;                         // [50000,64]
    float* lat0 = ob + 3200000;               // x0
    float* lat1 = ob + 9600000;               // x0 (copy)
    float* lat2 = ob + 16000000;              // x1

    char* w = (char*)d_ws;
    u16*   Abuf   = (u16*)(w + 0);            // 50000*512*2 = 51,200,000
    u16*   xbf0   = (u16*)(w + 51200000);     // 12,800,000
    u16*   xbf1   = (u16*)(w + 64000000);     // 12,800,000
    u16*   Bswc0  = (u16*)(w + 76800000);     // 163,840
    u16*   Bswc1  = (u16*)(w + 76963840);     // 163,840
    u16*   Bswc2  = (u16*)(w + 77127680);     // 81,920
    u16*   Bswp   = (u16*)(w + 77209600);     // 65,536
    u16*   Bswa   = (u16*)(w + 77275136);     // 65,536
    int*   rowptr = (int*)(w + 77340672);     // 400001*4 (pad to 1,600,064)
    int*   fill   = (int*)(w + 78940736);     // 1,600,000
    int*   epk    = (int*)(w + 80540736);     // 2,400,000
    int*   bsum   = (int*)(w + 82940736);     // 2,048

    // ---- all weight repacks, one dispatch ----
    build_bsw_all<<<1056, 256, 0, stream>>>(W_paper, W_author, bases0, root0,
                                            bases1, root1, bases2, root2,
                                            Bswp, Bswa, Bswc0, Bswc1, Bswc2);

    // ---- projections: x0 = relu(x @ W + b) -> lat0, lat1 (fp32) + xbf0 (bf16) ----
    proj2_kernel<<<dim3((NPER + 63) / 64, 2), 256, 0, stream>>>(
        x_paper, x_author, Bswp, Bswa, b_paper, b_author, lat0, lat1, xbf0);

    // ---- CSR over (dst, rel) segments (shared by all 3 convs) ----
    hipMemsetAsync(rowptr, 0, (NSEG + 1) * sizeof(int), stream);
    hist_kernel<<<(NEDGE + 255) / 256, 256, 0, stream>>>(ei, et, rowptr);
    int nchunk = (NSEG + 1 + SCAN_CHUNK - 1) / SCAN_CHUNK;   // 391
    scan1_kernel<<<nchunk, 256, 0, stream>>>(rowptr, NSEG + 1, bsum);
    scan2_kernel<<<1, 512, 0, stream>>>(bsum, nchunk);
    scan3_kernel<<<nchunk, 256, 0, stream>>>(rowptr, NSEG + 1, bsum, fill);
    scatter_kernel<<<(NEDGE + 255) / 256, 256, 0, stream>>>(ei, et, fill, epk);

    // ---- conv0: x1 = relu(rgcn(x0)) -> lat2 (fp32) + xbf1 (bf16) ----
    agg_kernel<<<NNODE / 4, 256, 0, stream>>>(xbf0, comp0, rowptr, epk, Abuf);
    gemm_kernel<512, true, 2, 2, 8, true, false, false><<<(NNODE + 63) / 64, 128, 0, stream>>>(
        Abuf, xbf0, Bswc0, bias0, NNODE, lat2, nullptr, xbf1, nullptr, HIDD);

    // ---- conv1: x2 = x1 + relu(rgcn(x1)) -> xbf0 (bf16 only; x2 not an output) ----
    agg_kernel<<<NNODE / 4, 256, 0, stream>>>(xbf1, comp1, rowptr, epk, Abuf);
    gemm_kernel<512, true, 2, 2, 8, true, true, false><<<(NNODE + 63) / 64, 128, 0, stream>>>(
        Abuf, xbf1, Bswc1, bias1, NNODE, nullptr, nullptr, xbf0, lat2, HIDD);

    // ---- conv2: out = rgcn(x2) (no relu) -> outF fp32 ----
    agg_kernel<<<NNODE / 4, 256, 0, stream>>>(xbf0, comp2, rowptr, epk, Abuf);
    gemm_kernel<512, true, 2, 2, 4, false, false, false><<<(NNODE + 63) / 64, 128, 0, stream>>>(
        Abuf, xbf0, Bswc2, bias2, NNODE, outF, nullptr, nullptr, nullptr, OUTD);
}